// Round 1
// baseline (986.832 us; speedup 1.0000x reference)
//
#include <hip/hip_runtime.h>
#include <stdint.h>

#define T_MASK 4194303u          // T = 2^22, power of two -> mask
#define PI2_C  2654435761u

// floor(16 * 1.26^l) for l=0..15, verified in fp32
__constant__ float c_NL[16] = {
    16.f, 20.f, 25.f, 32.f, 40.f, 50.f, 64.f, 80.f,
    101.f, 128.f, 161.f, 203.f, 256.f, 322.f, 406.f, 512.f
};

__global__ __launch_bounds__(256) void enc_cubic_kernel(
    const float* __restrict__ x,
    const float* __restrict__ ht,
    float* __restrict__ out,
    int npts)
{
    int tid = blockIdx.x * 256 + threadIdx.x;
    int n = tid >> 4;      // point index
    int l = tid & 15;      // level index
    if (n >= npts) return;

    float NL = c_NL[l];
    float px = x[2 * n];
    float py = x[2 * n + 1];

    float xs = px * NL;
    float ys = py * NL;
    int ix = (int)xs;      // x in [0,1): trunc == floor
    int iy = (int)ys;
    float tx = xs - (float)ix;
    float ty = ys - (float)iy;

    // Catmull-Rom weights (equivalent to reference's Hermite/B_MAT path)
    float tx2 = tx * tx, tx3 = tx2 * tx;
    float ty2 = ty * ty, ty3 = ty2 * ty;
    float wx0 = -0.5f * tx + tx2 - 0.5f * tx3;
    float wx1 = 1.0f - 2.5f * tx2 + 1.5f * tx3;
    float wx2 = 0.5f * tx + 2.0f * tx2 - 1.5f * tx3;
    float wx3 = -0.5f * tx2 + 0.5f * tx3;
    float wy0 = -0.5f * ty + ty2 - 0.5f * ty3;
    float wy1 = 1.0f - 2.5f * ty2 + 1.5f * ty3;
    float wy2 = 0.5f * ty + 2.0f * ty2 - 1.5f * ty3;
    float wy3 = -0.5f * ty2 + 0.5f * ty3;

    // 16 hashes
    uint32_t hx[4], hy[4];
    #pragma unroll
    for (int i = 0; i < 4; ++i) hx[i] = (uint32_t)(ix + i);
    #pragma unroll
    for (int j = 0; j < 4; ++j) hy[j] = (uint32_t)(iy + j) * PI2_C;

    // layout: hash_table[t, c, l] at t*32 + c*16 + l
    const float* base = ht + l;
    float f0[16], f1[16];
    #pragma unroll
    for (int j = 0; j < 4; ++j) {
        #pragma unroll
        for (int i = 0; i < 4; ++i) {
            uint32_t h = (hx[i] ^ hy[j]) & T_MASK;
            const float* p = base + (size_t)h * 32u;
            f0[j * 4 + i] = p[0];
            f1[j * 4 + i] = p[16];
        }
    }

    float wxa[4] = {wx0, wx1, wx2, wx3};
    float wya[4] = {wy0, wy1, wy2, wy3};
    float acc0 = 0.f, acc1 = 0.f;
    #pragma unroll
    for (int j = 0; j < 4; ++j) {
        float r0 = wxa[0] * f0[j * 4 + 0] + wxa[1] * f0[j * 4 + 1]
                 + wxa[2] * f0[j * 4 + 2] + wxa[3] * f0[j * 4 + 3];
        float r1 = wxa[0] * f1[j * 4 + 0] + wxa[1] * f1[j * 4 + 1]
                 + wxa[2] * f1[j * 4 + 2] + wxa[3] * f1[j * 4 + 3];
        acc0 += wya[j] * r0;
        acc1 += wya[j] * r1;
    }

    // out[n, l*2 + c] -> coalesced float2 store
    float2* o = (float2*)(out + (size_t)n * 32 + l * 2);
    *o = make_float2(acc0, acc1);
}

extern "C" void kernel_launch(void* const* d_in, const int* in_sizes, int n_in,
                              void* d_out, int out_size, void* d_ws, size_t ws_size,
                              hipStream_t stream) {
    const float* x  = (const float*)d_in[0];
    const float* ht = (const float*)d_in[1];
    float* out = (float*)d_out;
    int npts = in_sizes[0] / 2;           // x is (N, 2)
    int total = npts * 16;                // one thread per (point, level)
    int blocks = (total + 255) / 256;
    enc_cubic_kernel<<<blocks, 256, 0, stream>>>(x, ht, out, npts);
}

// Round 2
// 773.740 us; speedup vs baseline: 1.2754x; 1.2754x over previous
//
#include <hip/hip_runtime.h>
#include <stdint.h>

#define T_MASK 4194303u          // T = 2^22
#define PI2_C  2654435761u
#define NBKT   16384             // 128x128 Morton buckets

__constant__ float c_NL[16] = {
    16.f, 20.f, 25.f, 32.f, 40.f, 50.f, 64.f, 80.f,
    101.f, 128.f, 161.f, 203.f, 256.f, 322.f, 406.f, 512.f
};

__device__ __forceinline__ uint32_t part1by1(uint32_t v) {
    v &= 0xffu;
    v = (v | (v << 4)) & 0x0F0Fu;
    v = (v | (v << 2)) & 0x3333u;
    v = (v | (v << 1)) & 0x5555u;
    return v;
}

__global__ __launch_bounds__(256) void zero_counts(uint32_t* counts) {
    int i = blockIdx.x * 256 + threadIdx.x;
    if (i < NBKT) counts[i] = 0;
}

__global__ __launch_bounds__(256) void hist_kernel(
    const float* __restrict__ x, uint32_t* __restrict__ keys,
    uint32_t* __restrict__ counts, int npts)
{
    int i = blockIdx.x * 256 + threadIdx.x;
    if (i >= npts) return;
    float px = x[2 * i], py = x[2 * i + 1];
    int cx = (int)(px * 128.f); cx = cx < 0 ? 0 : (cx > 127 ? 127 : cx);
    int cy = (int)(py * 128.f); cy = cy < 0 ? 0 : (cy > 127 ? 127 : cy);
    uint32_t key = part1by1((uint32_t)cx) | (part1by1((uint32_t)cy) << 1);
    keys[i] = key;
    atomicAdd(&counts[key], 1u);
}

// single block, 1024 threads: in-place exclusive prefix scan of counts[NBKT]
__global__ __launch_bounds__(1024) void scan_kernel(uint32_t* __restrict__ counts) {
    __shared__ uint32_t sums[1024];
    int t = threadIdx.x;
    uint32_t local[NBKT / 1024];
    uint32_t s = 0;
    #pragma unroll
    for (int i = 0; i < NBKT / 1024; ++i) {
        local[i] = counts[t * (NBKT / 1024) + i];
        s += local[i];
    }
    sums[t] = s;
    __syncthreads();
    for (int off = 1; off < 1024; off <<= 1) {
        uint32_t v = (t >= off) ? sums[t - off] : 0u;
        __syncthreads();
        sums[t] += v;
        __syncthreads();
    }
    uint32_t run = (t > 0) ? sums[t - 1] : 0u;
    #pragma unroll
    for (int i = 0; i < NBKT / 1024; ++i) {
        uint32_t c = local[i];
        counts[t * (NBKT / 1024) + i] = run;
        run += c;
    }
}

__global__ __launch_bounds__(256) void scatter_kernel(
    const uint32_t* __restrict__ keys, uint32_t* __restrict__ offsets,
    uint32_t* __restrict__ order, int npts)
{
    int i = blockIdx.x * 256 + threadIdx.x;
    if (i >= npts) return;
    uint32_t pos = atomicAdd(&offsets[keys[i]], 1u);
    order[pos] = (uint32_t)i;
}

__global__ __launch_bounds__(256) void enc_cubic_kernel(
    const float* __restrict__ x,
    const float* __restrict__ ht,
    const uint32_t* __restrict__ order,
    float* __restrict__ out,
    int npts)
{
    // XCD swizzle: consecutive spatial ranks land on the same XCD's L2
    uint32_t bid = blockIdx.x;
    uint32_t nb = gridDim.x;
    if ((nb & 7u) == 0u) {
        uint32_t chunk = nb >> 3;
        bid = (bid & 7u) * chunk + (bid >> 3);
    }
    int tid = bid * 256 + threadIdx.x;
    int r = tid >> 4;      // sorted rank
    int l = tid & 15;      // level
    if (r >= npts) return;
    int n = (int)order[r];

    float NL = c_NL[l];
    float px = x[2 * n];
    float py = x[2 * n + 1];

    float xs = px * NL;
    float ys = py * NL;
    int ix = (int)xs;
    int iy = (int)ys;
    float tx = xs - (float)ix;
    float ty = ys - (float)iy;

    float tx2 = tx * tx, tx3 = tx2 * tx;
    float ty2 = ty * ty, ty3 = ty2 * ty;
    float wxa[4], wya[4];
    wxa[0] = -0.5f * tx + tx2 - 0.5f * tx3;
    wxa[1] = 1.0f - 2.5f * tx2 + 1.5f * tx3;
    wxa[2] = 0.5f * tx + 2.0f * tx2 - 1.5f * tx3;
    wxa[3] = -0.5f * tx2 + 0.5f * tx3;
    wya[0] = -0.5f * ty + ty2 - 0.5f * ty3;
    wya[1] = 1.0f - 2.5f * ty2 + 1.5f * ty3;
    wya[2] = 0.5f * ty + 2.0f * ty2 - 1.5f * ty3;
    wya[3] = -0.5f * ty2 + 0.5f * ty3;

    uint32_t hx[4], hy[4];
    #pragma unroll
    for (int i = 0; i < 4; ++i) hx[i] = (uint32_t)(ix + i);
    #pragma unroll
    for (int j = 0; j < 4; ++j) hy[j] = (uint32_t)(iy + j) * PI2_C;

    const float* base = ht + l;
    float f0[16], f1[16];
    #pragma unroll
    for (int j = 0; j < 4; ++j) {
        #pragma unroll
        for (int i = 0; i < 4; ++i) {
            uint32_t h = (hx[i] ^ hy[j]) & T_MASK;
            const float* p = base + (size_t)h * 32u;
            f0[j * 4 + i] = p[0];
            f1[j * 4 + i] = p[16];
        }
    }

    float acc0 = 0.f, acc1 = 0.f;
    #pragma unroll
    for (int j = 0; j < 4; ++j) {
        float r0 = wxa[0] * f0[j * 4 + 0] + wxa[1] * f0[j * 4 + 1]
                 + wxa[2] * f0[j * 4 + 2] + wxa[3] * f0[j * 4 + 3];
        float r1 = wxa[0] * f1[j * 4 + 0] + wxa[1] * f1[j * 4 + 1]
                 + wxa[2] * f1[j * 4 + 2] + wxa[3] * f1[j * 4 + 3];
        acc0 += wya[j] * r0;
        acc1 += wya[j] * r1;
    }

    float2* o = (float2*)(out + (size_t)n * 32 + l * 2);
    *o = make_float2(acc0, acc1);
}

extern "C" void kernel_launch(void* const* d_in, const int* in_sizes, int n_in,
                              void* d_out, int out_size, void* d_ws, size_t ws_size,
                              hipStream_t stream) {
    const float* x  = (const float*)d_in[0];
    const float* ht = (const float*)d_in[1];
    float* out = (float*)d_out;
    int npts = in_sizes[0] / 2;

    // workspace layout: counts[NBKT] | keys[npts] | order[npts]
    uint32_t* counts = (uint32_t*)d_ws;
    uint32_t* keys   = counts + NBKT;
    uint32_t* order  = keys + npts;

    int pb = (npts + 255) / 256;
    zero_counts<<<(NBKT + 255) / 256, 256, 0, stream>>>(counts);
    hist_kernel<<<pb, 256, 0, stream>>>(x, keys, counts, npts);
    scan_kernel<<<1, 1024, 0, stream>>>(counts);
    scatter_kernel<<<pb, 256, 0, stream>>>(keys, counts, order, npts);

    int total = npts * 16;
    int blocks = (total + 255) / 256;
    enc_cubic_kernel<<<blocks, 256, 0, stream>>>(x, ht, order, out, npts);
}

// Round 3
// 737.887 us; speedup vs baseline: 1.3374x; 1.0486x over previous
//
#include <hip/hip_runtime.h>
#include <stdint.h>

#define T_MASK 4194303u          // T = 2^22
#define PI2_C  2654435761u
#define NBKT   16384             // 128x128 Morton buckets

__constant__ float c_NL[16] = {
    16.f, 20.f, 25.f, 32.f, 40.f, 50.f, 64.f, 80.f,
    101.f, 128.f, 161.f, 203.f, 256.f, 322.f, 406.f, 512.f
};

__device__ __forceinline__ uint32_t part1by1(uint32_t v) {
    v &= 0xffu;
    v = (v | (v << 4)) & 0x0F0Fu;
    v = (v | (v << 2)) & 0x3333u;
    v = (v | (v << 1)) & 0x5555u;
    return v;
}

__global__ __launch_bounds__(256) void zero_counts(uint32_t* counts) {
    int i = blockIdx.x * 256 + threadIdx.x;
    if (i < NBKT) counts[i] = 0;
}

__global__ __launch_bounds__(256) void hist_kernel(
    const float* __restrict__ x, uint32_t* __restrict__ keys,
    uint32_t* __restrict__ counts, int npts)
{
    int i = blockIdx.x * 256 + threadIdx.x;
    if (i >= npts) return;
    float px = x[2 * i], py = x[2 * i + 1];
    int cx = (int)(px * 128.f); cx = cx < 0 ? 0 : (cx > 127 ? 127 : cx);
    int cy = (int)(py * 128.f); cy = cy < 0 ? 0 : (cy > 127 ? 127 : cy);
    uint32_t key = part1by1((uint32_t)cx) | (part1by1((uint32_t)cy) << 1);
    keys[i] = key;
    atomicAdd(&counts[key], 1u);
}

// single block, 1024 threads: in-place exclusive prefix scan of counts[NBKT]
__global__ __launch_bounds__(1024) void scan_kernel(uint32_t* __restrict__ counts) {
    __shared__ uint32_t sums[1024];
    int t = threadIdx.x;
    uint32_t local[NBKT / 1024];
    uint32_t s = 0;
    #pragma unroll
    for (int i = 0; i < NBKT / 1024; ++i) {
        local[i] = counts[t * (NBKT / 1024) + i];
        s += local[i];
    }
    sums[t] = s;
    __syncthreads();
    for (int off = 1; off < 1024; off <<= 1) {
        uint32_t v = (t >= off) ? sums[t - off] : 0u;
        __syncthreads();
        sums[t] += v;
        __syncthreads();
    }
    uint32_t run = (t > 0) ? sums[t - 1] : 0u;
    #pragma unroll
    for (int i = 0; i < NBKT / 1024; ++i) {
        uint32_t c = local[i];
        counts[t * (NBKT / 1024) + i] = run;
        run += c;
    }
}

__global__ __launch_bounds__(256) void scatter_kernel(
    const uint32_t* __restrict__ keys, uint32_t* __restrict__ offsets,
    uint32_t* __restrict__ order, int npts)
{
    int i = blockIdx.x * 256 + threadIdx.x;
    if (i >= npts) return;
    uint32_t pos = atomicAdd(&offsets[keys[i]], 1u);
    order[pos] = (uint32_t)i;
}

// wave = 64 spatially-consecutive (sorted) points at ONE level -> tap loads
// coalesce across lanes at coarse levels. Level rotated diagonally per group
// to avoid static level->XCD binding (16 levels = 0 mod 8 XCDs).
__global__ __launch_bounds__(256) void enc_cubic_kernel(
    const float* __restrict__ x,
    const float* __restrict__ ht,
    const uint32_t* __restrict__ order,
    float* __restrict__ out,
    int npts)
{
    uint32_t bid = blockIdx.x;
    uint32_t nb = gridDim.x;
    if ((nb & 7u) == 0u) {
        uint32_t chunk = nb >> 3;
        bid = (bid & 7u) * chunk + (bid >> 3);
    }
    uint32_t tid = bid * 256u + threadIdx.x;
    uint32_t w = tid >> 6;           // global wave id
    uint32_t lane = tid & 63u;
    uint32_t g = w >> 4;             // group of 64 points
    uint32_t l = (w + g) & 15u;      // diagonal level rotation
    uint32_t r = g * 64u + lane;     // sorted rank
    if (r >= (uint32_t)npts) return;
    int n = (int)order[r];

    float NL = c_NL[l];
    float px = x[2 * n];
    float py = x[2 * n + 1];

    float xs = px * NL;
    float ys = py * NL;
    int ix = (int)xs;
    int iy = (int)ys;
    float tx = xs - (float)ix;
    float ty = ys - (float)iy;

    float tx2 = tx * tx, tx3 = tx2 * tx;
    float ty2 = ty * ty, ty3 = ty2 * ty;
    float wxa[4], wya[4];
    wxa[0] = -0.5f * tx + tx2 - 0.5f * tx3;
    wxa[1] = 1.0f - 2.5f * tx2 + 1.5f * tx3;
    wxa[2] = 0.5f * tx + 2.0f * tx2 - 1.5f * tx3;
    wxa[3] = -0.5f * tx2 + 0.5f * tx3;
    wya[0] = -0.5f * ty + ty2 - 0.5f * ty3;
    wya[1] = 1.0f - 2.5f * ty2 + 1.5f * ty3;
    wya[2] = 0.5f * ty + 2.0f * ty2 - 1.5f * ty3;
    wya[3] = -0.5f * ty2 + 0.5f * ty3;

    uint32_t hx[4], hy[4];
    #pragma unroll
    for (int i = 0; i < 4; ++i) hx[i] = (uint32_t)(ix + i);
    #pragma unroll
    for (int j = 0; j < 4; ++j) hy[j] = (uint32_t)(iy + j) * PI2_C;

    const float* base = ht + l;
    float acc0 = 0.f, acc1 = 0.f;
    #pragma unroll
    for (int j = 0; j < 4; ++j) {
        float r0 = 0.f, r1 = 0.f;
        #pragma unroll
        for (int i = 0; i < 4; ++i) {
            uint32_t h = (hx[i] ^ hy[j]) & T_MASK;
            const float* p = base + (size_t)h * 32u;
            r0 += wxa[i] * p[0];
            r1 += wxa[i] * p[16];
        }
        acc0 += wya[j] * r0;
        acc1 += wya[j] * r1;
    }

    float2* o = (float2*)(out + (size_t)n * 32 + l * 2);
    *o = make_float2(acc0, acc1);
}

extern "C" void kernel_launch(void* const* d_in, const int* in_sizes, int n_in,
                              void* d_out, int out_size, void* d_ws, size_t ws_size,
                              hipStream_t stream) {
    const float* x  = (const float*)d_in[0];
    const float* ht = (const float*)d_in[1];
    float* out = (float*)d_out;
    int npts = in_sizes[0] / 2;

    // workspace layout: counts[NBKT] | keys[npts] | order[npts]
    uint32_t* counts = (uint32_t*)d_ws;
    uint32_t* keys   = counts + NBKT;
    uint32_t* order  = keys + npts;

    int pb = (npts + 255) / 256;
    zero_counts<<<(NBKT + 255) / 256, 256, 0, stream>>>(counts);
    hist_kernel<<<pb, 256, 0, stream>>>(x, keys, counts, npts);
    scan_kernel<<<1, 1024, 0, stream>>>(counts);
    scatter_kernel<<<pb, 256, 0, stream>>>(keys, counts, order, npts);

    int total = npts * 16;
    int blocks = (total + 255) / 256;
    enc_cubic_kernel<<<blocks, 256, 0, stream>>>(x, ht, order, out, npts);
}